// Round 2
// baseline (286.682 us; speedup 1.0000x reference)
//
#include <hip/hip_runtime.h>

// RPN target generation for MI355X.
// Outputs (float32, concatenated): [0,A) rpn_match; [A,5A) rpn_bbox (A x 4); [5A] num_positives.
// ws: G x u64 per-gt argmax keys (key = (iou_bits+1)<<32 | (0xFFFFFFFF - anchor_idx); 0 = none).

#define GMAX 256

__device__ __forceinline__ unsigned long long shfl_down_u64(unsigned long long x, int off) {
    unsigned lo = (unsigned)__shfl_down((int)(unsigned)(x & 0xFFFFFFFFull), off);
    unsigned hi = (unsigned)__shfl_down((int)(unsigned)(x >> 32), off);
    return (((unsigned long long)hi) << 32) | lo;
}

// Faithful to the reference, including the intentional size "bug":
// gt_size = y2 + y1 (not y2 - y1); centre = 0.5 * size.
__device__ __forceinline__ float4 compute_deltas(float4 ab, float4 gb,
                                                 const float* __restrict__ sd) {
    float sy_g = gb.z + gb.x;   // box = (y1, x1, y2, x2) in (x,y,z,w)
    float sx_g = gb.w + gb.y;
    float sy_a = ab.z + ab.x;
    float sx_a = ab.w + ab.y;
    float4 d;
    d.x = (0.5f * (sy_g - sy_a) / sy_a) / sd[0];
    d.y = (0.5f * (sx_g - sx_a) / sx_a) / sd[1];
    d.z = logf(sy_g / sy_a) / sd[2];
    d.w = logf(sx_g / sx_a) / sd[3];
    return d;
}

__global__ __launch_bounds__(256) void rpn_pass1(
    const float4* __restrict__ anchors,       // [A]
    const int* __restrict__ valid,            // [A] jnp bool delivered as int32
    const int* __restrict__ cls,              // [G]
    const float4* __restrict__ gt,            // [G]
    const float* __restrict__ stdev,          // [4]
    float* __restrict__ out,                  // [5A+1]
    unsigned long long* __restrict__ gkey,    // [G], pre-zeroed
    int A, int G)
{
    __shared__ float4 s_gt[GMAX];
    __shared__ float s_area[GMAX];
    __shared__ float s_crowdf[GMAX];          // 1.0 if crowd else 0.0
    __shared__ unsigned long long s_key[GMAX];
    __shared__ int s_anycrowd;
    __shared__ int s_cnt;

    const int tid = threadIdx.x;
    if (tid == 0) { s_anycrowd = 0; s_cnt = 0; }
    if (tid < G) {
        float4 b = gt[tid];
        s_gt[tid] = b;
        s_area[tid] = (b.z - b.x) * (b.w - b.y);
        int c = cls[tid];
        float cf = (c < 0) ? 1.0f : 0.0f;
        s_crowdf[tid] = cf;
        if (c < 0) s_anycrowd = 1;            // benign race, same value
        s_key[tid] = 0ULL;
    }
    __syncthreads();
    const int any_crowd = s_anycrowd;

    const int ai = blockIdx.x * 256 + tid;
    const bool in_range = (ai < A);
    float4 ab = in_range ? anchors[ai] : make_float4(0.f, 0.f, 1.f, 1.f);
    const bool v = in_range && (valid[ai] != 0);
    const float a_area = (ab.z - ab.x) * (ab.w - ab.y);

    float best = -2.0f;                       // argmax over eff = (crowd ? -1 : iou)
    int bg = 0;
    float crowd_max = 0.0f;

    for (int g = 0; g < G; ++g) {
        float4 gb = s_gt[g];
        float y1 = fmaxf(ab.x, gb.x);
        float x1 = fmaxf(ab.y, gb.y);
        float y2 = fminf(ab.z, gb.z);
        float x2 = fminf(ab.w, gb.w);
        float ih = fmaxf(y2 - y1, 0.f);
        float iw = fmaxf(x2 - x1, 0.f);
        float inter = ih * iw;
        float uni = a_area + s_area[g] - inter;
        float iou = 0.0f;
        if (inter > 0.0f) iou = inter / uni;  // IEEE div: matches numpy ref
        float cf = s_crowdf[g];
        float eff = (cf != 0.0f) ? -1.0f : iou;
        if (eff > best) { best = eff; bg = g; }          // first-index tie-break
        crowd_max = fmaxf(crowd_max, iou * cf);

        // Per-gt argmax over valid anchors. Only reduce when some lane overlaps
        // (zero-iou valid anchors only matter via the pass-2 fallback path).
        bool contrib = v && (cf == 0.0f) && (inter > 0.0f);
        if (__any(contrib)) {
            unsigned key_hi = contrib ? (__float_as_uint(iou) + 1u) : 0u;
            unsigned long long key =
                (((unsigned long long)key_hi) << 32) |
                (unsigned long long)(0xFFFFFFFFu - (unsigned)ai);
            #pragma unroll
            for (int off = 32; off >= 1; off >>= 1) {
                unsigned long long o = shfl_down_u64(key, off);
                if (o > key) key = o;
            }
            if ((tid & 63) == 0) atomicMax(&s_key[g], key);
        }
    }

    // provisional positivity (pos_from_gt applied in pass 2)
    bool no_crowd = any_crowd ? (crowd_max < 0.001f) : true;
    bool pos = (best >= 0.7f);
    bool neg = (best < 0.3f) && no_crowd && !pos;

    unsigned long long pv = __ballot((int)(in_range && pos && v));
    if ((tid & 63) == 0) atomicAdd(&s_cnt, (int)__popcll(pv));
    __syncthreads();

    if (tid < G && s_key[tid] != 0ULL) atomicMax(&gkey[tid], s_key[tid]);
    if (tid == 0 && s_cnt > 0) atomicAdd(out + (size_t)5 * A, (float)s_cnt);

    if (in_range) {
        out[ai] = v ? (pos ? 1.0f : (neg ? -1.0f : 0.0f)) : 0.0f;
        float4 d = make_float4(0.f, 0.f, 0.f, 0.f);
        if (pos && v) d = compute_deltas(ab, s_gt[bg], stdev);
        ((float4*)(out + A))[ai] = d;
    }
}

__global__ __launch_bounds__(256) void rpn_pass2(
    const float4* __restrict__ anchors,
    const int* __restrict__ valid,
    const int* __restrict__ cls,
    const float4* __restrict__ gt,
    const float* __restrict__ stdev,
    float* __restrict__ out,
    const unsigned long long* __restrict__ gkey,
    int A, int G)
{
    __shared__ float4 s_gt[GMAX];
    __shared__ float s_area[GMAX];
    __shared__ float s_crowdf[GMAX];

    const int tid = threadIdx.x;
    if (tid < G) {
        float4 b = gt[tid];
        s_gt[tid] = b;
        s_area[tid] = (b.z - b.x) * (b.w - b.y);
        s_crowdf[tid] = (cls[tid] < 0) ? 1.0f : 0.0f;
    }
    __syncthreads();

    if (tid >= G) return;
    if (s_crowdf[tid] != 0.0f) return;        // scatter value is False for crowd gts

    unsigned long long key = gkey[tid];
    int w;
    if (key != 0ULL) {
        w = (int)(0xFFFFFFFFu - (unsigned)(key & 0xFFFFFFFFull));
    } else {
        // No valid anchor overlapped this gt: reference argmax picks the first
        // valid anchor (column value 0.0 beats the -1.0 of invalid anchors),
        // or index 0 if no anchor is valid at all.
        w = 0;
        for (int i = 0; i < A; ++i) { if (valid[i] != 0) { w = i; break; } }
    }
    if (valid[w] == 0) return;                // positive but masked -> invisible

    float old = atomicExch(out + w, 1.0f);    // dedup across gts picking same anchor
    if (old == 1.0f) return;                  // already positive (counted, bbox set)

    // flip to positive: recompute this anchor's gt-argmax for the deltas
    float4 ab = anchors[w];
    float a_area = (ab.z - ab.x) * (ab.w - ab.y);
    float best = -2.0f; int bg = 0;
    for (int g = 0; g < G; ++g) {
        float4 gb = s_gt[g];
        float y1 = fmaxf(ab.x, gb.x);
        float x1 = fmaxf(ab.y, gb.y);
        float y2 = fminf(ab.z, gb.z);
        float x2 = fminf(ab.w, gb.w);
        float inter = fmaxf(y2 - y1, 0.f) * fmaxf(x2 - x1, 0.f);
        float uni = a_area + s_area[g] - inter;
        float iou = 0.0f;
        if (inter > 0.0f) iou = inter / uni;
        float eff = (s_crowdf[g] != 0.0f) ? -1.0f : iou;
        if (eff > best) { best = eff; bg = g; }
    }
    ((float4*)(out + A))[w] = compute_deltas(ab, s_gt[bg], stdev);
    atomicAdd(out + (size_t)5 * A, 1.0f);
}

extern "C" void kernel_launch(void* const* d_in, const int* in_sizes, int n_in,
                              void* d_out, int out_size, void* d_ws, size_t ws_size,
                              hipStream_t stream) {
    const float4* anchors = (const float4*)d_in[0];
    const int* valid      = (const int*)d_in[1];   // jnp bool -> int32 per element
    const int* cls        = (const int*)d_in[2];
    const float4* gt      = (const float4*)d_in[3];
    const float* stdev    = (const float*)d_in[4];
    float* out            = (float*)d_out;

    const int A = in_sizes[0] / 4;
    const int G = in_sizes[2];                 // 256

    unsigned long long* gkey = (unsigned long long*)d_ws;
    hipMemsetAsync((void*)gkey, 0, (size_t)G * sizeof(unsigned long long), stream);
    hipMemsetAsync((void*)(out + (size_t)5 * A), 0, sizeof(float), stream);

    const int blocks = (A + 255) / 256;        // 1023 for A=261888
    rpn_pass1<<<blocks, 256, 0, stream>>>(anchors, valid, cls, gt, stdev, out, gkey, A, G);
    rpn_pass2<<<1, 256, 0, stream>>>(anchors, valid, cls, gt, stdev, out, gkey, A, G);
}

// Round 3
// 246.270 us; speedup vs baseline: 1.1641x; 1.1641x over previous
//
#include <hip/hip_runtime.h>

// RPN target generation for MI355X — single fused kernel.
// Outputs (float32, concat): [0,A) rpn_match; [A,5A) rpn_bbox (A x 4); [5A] num_positives.
// ws layout: [0,2048) gkey (G x u64 packed argmax keys), [2048] u32 done-counter,
//            [2052] i32 positive count. All pre-zeroed by one memset.

#define GMAX 256

// Faithful to the reference, including the intentional size "bug":
// gt_size = y2 + y1 (not y2 - y1); centre = 0.5 * (y1 + y2).
__device__ __forceinline__ float4 compute_deltas(float4 ab, float4 gb,
                                                 const float* __restrict__ sd) {
    float sy_g = gb.z + gb.x;   // box = (y1, x1, y2, x2) in (x,y,z,w)
    float sx_g = gb.w + gb.y;
    float sy_a = ab.z + ab.x;
    float sx_a = ab.w + ab.y;
    float4 d;
    d.x = (0.5f * (sy_g - sy_a) / sy_a) / sd[0];
    d.y = (0.5f * (sx_g - sx_a) / sx_a) / sd[1];
    d.z = logf(sy_g / sy_a) / sd[2];
    d.w = logf(sx_g / sx_a) / sd[3];
    return d;
}

__global__ __launch_bounds__(256) void rpn_fused(
    const float4* __restrict__ anchors,       // [A]
    const int* __restrict__ valid,            // [A] jnp bool delivered as int32
    const int* __restrict__ cls,              // [G]
    const float4* __restrict__ gt,            // [G]
    const float* __restrict__ stdev,          // [4]
    float* __restrict__ out,                  // [5A+1]
    unsigned long long* __restrict__ gkey,    // [G] in ws, pre-zeroed
    unsigned* __restrict__ done,              // in ws, pre-zeroed
    int* __restrict__ cnt,                    // in ws, pre-zeroed
    int A, int G)
{
    __shared__ float4 s_gt[GMAX];
    __shared__ float s_area[GMAX];
    __shared__ float s_crowdf[GMAX];          // 1.0 if crowd else 0.0
    __shared__ unsigned long long s_key[GMAX];
    __shared__ int s_anycrowd;
    __shared__ int s_cnt;
    __shared__ int s_islast;

    const int tid = threadIdx.x;
    if (tid == 0) { s_anycrowd = 0; s_cnt = 0; }
    if (tid < G) {
        float4 b = gt[tid];
        s_gt[tid] = b;
        s_area[tid] = (b.z - b.x) * (b.w - b.y);
        int c = cls[tid];
        s_crowdf[tid] = (c < 0) ? 1.0f : 0.0f;
        if (c < 0) s_anycrowd = 1;            // benign race, same value
        s_key[tid] = 0ULL;
    }
    __syncthreads();
    const int any_crowd = s_anycrowd;

    const int ai = blockIdx.x * 256 + tid;
    const bool in_range = (ai < A);
    float4 ab = in_range ? anchors[ai] : make_float4(0.f, 0.f, 1.f, 1.f);
    const bool v = in_range && (valid[ai] != 0);
    const float a_area = (ab.z - ab.x) * (ab.w - ab.y);
    const unsigned lokey = 0xFFFFFFFFu - (unsigned)ai;   // smaller ai -> larger lokey

    float best;
    int bg = 0;
    float crowd_max = 0.0f;

    if (!any_crowd) {
        // ---- fast path: no crowd gts ----
        best = -1.0f;                          // all ious >= 0
        #pragma unroll 4
        for (int g = 0; g < G; ++g) {
            float4 gb = s_gt[g];
            float y1 = fmaxf(ab.x, gb.x);
            float x1 = fmaxf(ab.y, gb.y);
            float y2 = fminf(ab.z, gb.z);
            float x2 = fminf(ab.w, gb.w);
            float inter = fmaxf(y2 - y1, 0.f) * fmaxf(x2 - x1, 0.f);
            float iou = 0.0f;
            if (inter > 0.0f)
                iou = inter / (a_area + s_area[g] - inter);   // IEEE div, matches np
            if (iou > best) { best = iou; bg = g; }           // first-index tie-break
            if (v && inter > 0.0f) {
                unsigned long long key =
                    (((unsigned long long)(__float_as_uint(iou) + 1u)) << 32) | lokey;
                atomicMax(&s_key[g], key);     // ~1.4 lanes/wave contribute on avg
            }
        }
    } else {
        // ---- general path: crowd handling ----
        best = -2.0f;
        for (int g = 0; g < G; ++g) {
            float4 gb = s_gt[g];
            float y1 = fmaxf(ab.x, gb.x);
            float x1 = fmaxf(ab.y, gb.y);
            float y2 = fminf(ab.z, gb.z);
            float x2 = fminf(ab.w, gb.w);
            float inter = fmaxf(y2 - y1, 0.f) * fmaxf(x2 - x1, 0.f);
            float iou = 0.0f;
            if (inter > 0.0f)
                iou = inter / (a_area + s_area[g] - inter);
            float cf = s_crowdf[g];
            float eff = (cf != 0.0f) ? -1.0f : iou;
            if (eff > best) { best = eff; bg = g; }
            crowd_max = fmaxf(crowd_max, iou * cf);
            if (v && (cf == 0.0f) && inter > 0.0f) {
                unsigned long long key =
                    (((unsigned long long)(__float_as_uint(iou) + 1u)) << 32) | lokey;
                atomicMax(&s_key[g], key);
            }
        }
    }

    // provisional positivity (pos_from_gt applied by finalize)
    bool no_crowd = any_crowd ? (crowd_max < 0.001f) : true;
    bool pos = (best >= 0.7f);
    bool neg = (best < 0.3f) && no_crowd && !pos;

    unsigned long long pv = __ballot((int)(in_range && pos && v));
    if ((tid & 63) == 0) atomicAdd(&s_cnt, (int)__popcll(pv));

    if (in_range) {
        out[ai] = v ? (pos ? 1.0f : (neg ? -1.0f : 0.0f)) : 0.0f;
        float4 d = make_float4(0.f, 0.f, 0.f, 0.f);
        if (pos && v) d = compute_deltas(ab, s_gt[bg], stdev);
        ((float4*)(out + A))[ai] = d;
    }
    __syncthreads();

    if (tid < G && s_key[tid] != 0ULL) atomicMax(&gkey[tid], s_key[tid]);
    if (tid == 0 && s_cnt > 0) atomicAdd(cnt, s_cnt);

    // ---- last-block-done: finalize (pos_from_gt scatter + count) ----
    __threadfence();                           // publish out/gkey/cnt device-wide
    if (tid == 0) {
        unsigned prev = atomicAdd(done, 1u);
        s_islast = (prev == gridDim.x - 1);
        s_cnt = 0;                             // reuse as flip counter
    }
    __syncthreads();
    if (!s_islast) return;
    __threadfence();                           // acquire all blocks' writes

    if (tid < G && s_crowdf[tid] == 0.0f) {    // scatter value is False for crowd gts
        unsigned long long key = gkey[tid];
        int w;
        if (key != 0ULL) {
            w = (int)(0xFFFFFFFFu - (unsigned)(key & 0xFFFFFFFFull));
        } else {
            // No valid anchor overlapped this gt: reference argmax picks the first
            // valid anchor (0.0 beats the -1.0 of invalid), or 0 if none valid.
            w = 0;
            for (int i = 0; i < A; ++i) { if (valid[i] != 0) { w = i; break; } }
        }
        if (valid[w] != 0) {
            float old = atomicExch(out + w, 1.0f);   // dedup gts sharing a winner
            if (old != 1.0f) {
                // flip to positive: recompute this anchor's gt-argmax for deltas
                float4 ab2 = anchors[w];
                float a2 = (ab2.z - ab2.x) * (ab2.w - ab2.y);
                float b2 = -2.0f; int g2 = 0;
                for (int g = 0; g < G; ++g) {
                    float4 gb = s_gt[g];
                    float y1 = fmaxf(ab2.x, gb.x);
                    float x1 = fmaxf(ab2.y, gb.y);
                    float y2 = fminf(ab2.z, gb.z);
                    float x2 = fminf(ab2.w, gb.w);
                    float inter = fmaxf(y2 - y1, 0.f) * fmaxf(x2 - x1, 0.f);
                    float iou = 0.0f;
                    if (inter > 0.0f) iou = inter / (a2 + s_area[g] - inter);
                    float eff = (s_crowdf[g] != 0.0f) ? -1.0f : iou;
                    if (eff > b2) { b2 = eff; g2 = g; }
                }
                ((float4*)(out + A))[w] = compute_deltas(ab2, s_gt[g2], stdev);
                atomicAdd(&s_cnt, 1);
            }
        }
    }
    __syncthreads();
    if (tid == 0) out[(size_t)5 * A] = (float)(*cnt + s_cnt);
}

extern "C" void kernel_launch(void* const* d_in, const int* in_sizes, int n_in,
                              void* d_out, int out_size, void* d_ws, size_t ws_size,
                              hipStream_t stream) {
    const float4* anchors = (const float4*)d_in[0];
    const int* valid      = (const int*)d_in[1];   // jnp bool -> int32 per element
    const int* cls        = (const int*)d_in[2];
    const float4* gt      = (const float4*)d_in[3];
    const float* stdev    = (const float*)d_in[4];
    float* out            = (float*)d_out;

    const int A = in_sizes[0] / 4;
    const int G = in_sizes[2];                 // 256

    unsigned long long* gkey = (unsigned long long*)d_ws;
    unsigned* done = (unsigned*)((char*)d_ws + 2048);
    int* cnt       = (int*)((char*)d_ws + 2052);
    hipMemsetAsync(d_ws, 0, 2056, stream);

    const int blocks = (A + 255) / 256;        // 1023 for A=261888
    rpn_fused<<<blocks, 256, 0, stream>>>(anchors, valid, cls, gt, stdev, out,
                                          gkey, done, cnt, A, G);
}